// Round 1
// baseline (2064.600 us; speedup 1.0000x reference)
//
#include <hip/hip_runtime.h>

#define BATCH 128

constexpr float DM = 0.95122942450071400910f;  // exp(-1/20)
constexpr float DS = 0.81873075307798185867f;  // exp(-1/5)

// ---------------- sizes ----------------
constexpr int N_IN  = BATCH * 784;          // input_u
constexpr int N_INP = BATCH * 1024;         // padded input spikes (32x32)
constexpr int N_C1  = BATCH * 32 * 784;     // conv1 neuron state
constexpr int N_P1P = BATCH * 32 * 360;     // padded pooled conv1 spikes (18x20)
constexpr int N_C2  = BATCH * 64 * 196;     // conv2 neuron state
constexpr int N_P2  = BATCH * 3136;         // pooled conv2 spikes, flattened
constexpr int N_F1  = BATCH * 600;
constexpr int N_F2  = BATCH * 10;
constexpr int N_WT  = 3136 * 600;           // transposed fc1 weights

// ---------------- workspace offsets (floats) ----------------
constexpr size_t o_inu  = 0;
constexpr size_t o_insp = o_inu  + N_IN;
constexpr size_t o_um1  = o_insp + N_INP;
constexpr size_t o_us1  = o_um1  + N_C1;
constexpr size_t o_sav1 = o_us1  + N_C1;
constexpr size_t o_te1  = o_sav1 + N_C1;
constexpr size_t o_lat1 = o_te1  + N_C1;
constexpr size_t o_p1p  = o_lat1 + N_C1;
constexpr size_t o_um2  = o_p1p  + N_P1P;
constexpr size_t o_us2  = o_um2  + N_C2;
constexpr size_t o_sav2 = o_us2  + N_C2;
constexpr size_t o_te2  = o_sav2 + N_C2;
constexpr size_t o_lat2 = o_te2  + N_C2;
constexpr size_t o_p2   = o_lat2 + N_C2;
constexpr size_t o_f1um = o_p2   + N_P2;
constexpr size_t o_f1us = o_f1um + N_F1;
constexpr size_t o_f1sv = o_f1us + N_F1;
constexpr size_t o_f1sp = o_f1sv + N_F1;
constexpr size_t o_f2um = o_f1sp + N_F1;
constexpr size_t o_f2us = o_f2um + N_F2;
constexpr size_t o_f2sv = o_f2us + N_F2;
constexpr size_t o_outt = o_f2sv + N_F2;
constexpr size_t o_outu = o_outt + N_F2;
constexpr size_t o_tel  = o_outu + N_F2;
constexpr size_t o_nnz  = o_tel  + N_F2;    // [0..127]=nnz_in, [128..255]=nnz_pool1
constexpr size_t o_ssp  = o_nnz  + 256;     // 8 (5 used)
constexpr size_t o_wt   = o_ssp  + 8;
constexpr size_t TOTALF = o_wt   + N_WT;

// ---------------- helpers ----------------
__device__ __forceinline__ void spike_count_add(float v, float* red, float* dst) {
    int lane = threadIdx.x & 63;
    int wid  = threadIdx.x >> 6;
    #pragma unroll
    for (int o = 32; o; o >>= 1) v += __shfl_down(v, o, 64);
    if (lane == 0) red[wid] = v;
    __syncthreads();
    if (threadIdx.x == 0) {
        int nw = ((int)blockDim.x + 63) >> 6;
        float t = 0.f;
        for (int w = 0; w < nw; ++w) t += red[w];
        if (t != 0.f) atomicAdd(dst, t);
    }
}

__global__ void k_fill(float* p, size_t n, float v) {
    size_t i = (size_t)blockIdx.x * blockDim.x + threadIdx.x;
    size_t st = (size_t)gridDim.x * blockDim.x;
    for (; i < n; i += st) p[i] = v;
}

__global__ void k_transpose(const float* __restrict__ w, float* __restrict__ wt) {
    int i = blockIdx.x * 256 + threadIdx.x;
    if (i < 600 * 3136) {
        int j = i / 3136, k = i - j * 3136;
        wt[(size_t)k * 600 + j] = w[i];
    }
}

// ---------------- step kernels ----------------
// input encoding neuron: leaky integrator with spike-reset
__launch_bounds__(256)
__global__ void k_input(const float* __restrict__ inp, float* __restrict__ inu,
                        float* __restrict__ insp, float* __restrict__ nnzin,
                        float* __restrict__ ssp) {
    __shared__ float red[16];
    int idx = blockIdx.x * 256 + threadIdx.x;   // exact: 392*256 = 100352
    int b = idx / 784, p = idx - b * 784;
    int y = p / 28, x = p - y * 28;
    float* pin = insp + (size_t)b * 1024 + (y + 2) * 32 + (x + 2);
    float sprev = *pin;
    float u = inu[idx] * DM * (1.f - sprev) + inp[idx] * 0.3f;
    float s = (u > 1.0f) ? 1.f : 0.f;
    inu[idx] = u;
    *pin = s;
    if (s != 0.f) atomicAdd(&nnzin[b], 1.f);
    spike_count_add(s, red, &ssp[0]);
}

// conv1 (1->32, 5x5 pad2) + NOSO + te/lat + fused 2x2 latency min-pool
__launch_bounds__(832)
__global__ void k_conv1(const float* __restrict__ w1, const float* __restrict__ insp,
                        float* __restrict__ um, float* __restrict__ us,
                        float* __restrict__ sav, float* __restrict__ te,
                        float* __restrict__ lat, float* __restrict__ p1p,
                        const float* __restrict__ nnzin, float* __restrict__ nnz1,
                        float* __restrict__ ssp) {
    __shared__ float s_sp[784], s_lat[784], red[16];
    int bo = blockIdx.x;              // b*32 + oc
    int b = bo >> 5, oc = bo & 31;
    int tid = threadIdx.x;
    float s = 0.f;
    if (tid < 784) {
        int y = tid / 28, x = tid - y * 28;
        float c = 0.f;
        if (nnzin[b] != 0.f) {
            const float* ip = insp + (size_t)b * 1024 + y * 32 + x;
            const float* w = w1 + oc * 25;
            #pragma unroll
            for (int ky = 0; ky < 5; ++ky)
                #pragma unroll
                for (int kx = 0; kx < 5; ++kx)
                    c = fmaf(ip[ky * 32 + kx], w[ky * 5 + kx], c);
        }
        size_t gi = (size_t)bo * 784 + tid;
        float um_ = fmaf(um[gi], DM, c);
        float us_ = fmaf(us[gi], DS, c);
        float sv = sav[gi];
        float u = sv * (um_ - us_);
        s = (u > 1.0f) ? 1.f : 0.f;
        um[gi] = um_; us[gi] = us_; sav[gi] = sv * (1.f - s);
        float te_ = te[gi];
        te_ += ((te_ != 0.f) || (um_ != 0.f)) ? 1.f : 0.f;
        te[gi] = te_;
        float lt = lat[gi] + s * (te_ - 15.f);
        lat[gi] = lt;
        s_sp[tid] = s; s_lat[tid] = lt;
    }
    spike_count_add(tid < 784 ? s : 0.f, red, &ssp[1]);  // barrier inside
    if (tid < 196) {
        int py = tid / 14, px = tid - py * 14;
        int base = (2 * py) * 28 + 2 * px;
        float s00 = s_sp[base],      l00 = s_lat[base];
        float s01 = s_sp[base + 1],  l01 = s_lat[base + 1];
        float s10 = s_sp[base + 28], l10 = s_lat[base + 28];
        float s11 = s_sp[base + 29], l11 = s_lat[base + 29];
        float lmin = fminf(fminf(l00, l01), fminf(l10, l11));
        float o = fmaxf(fmaxf(l00 == lmin ? s00 : 0.f, l01 == lmin ? s01 : 0.f),
                        fmaxf(l10 == lmin ? s10 : 0.f, l11 == lmin ? s11 : 0.f));
        p1p[(size_t)bo * 360 + (py + 2) * 20 + (px + 2)] = o;
        if (o != 0.f) atomicAdd(&nnz1[b], 1.f);
    }
}

// conv2 (32->64, 5x5 pad2) + NOSO + te/lat + fused pool -> flattened fc1 input
__launch_bounds__(256)
__global__ void k_conv2(const float* __restrict__ w2, const float* __restrict__ p1p,
                        float* __restrict__ um, float* __restrict__ us,
                        float* __restrict__ sav, float* __restrict__ te,
                        float* __restrict__ lat, float* __restrict__ p2,
                        const float* __restrict__ nnz1, float* __restrict__ ssp) {
    __shared__ float s_sp[196], s_lat[196], red[16];
    int bo = blockIdx.x;              // b*64 + oc
    int b = bo >> 6, oc = bo & 63;
    int tid = threadIdx.x;
    float s = 0.f;
    if (tid < 196) {
        int y = tid / 14, x = tid - y * 14;
        float c = 0.f;
        if (nnz1[b] != 0.f) {
            const float* ipb = p1p + (size_t)b * (32 * 360) + y * 20 + x;
            const float* wb = w2 + oc * 800;
            float c0 = 0.f, c1 = 0.f, c2 = 0.f, c3 = 0.f;
            for (int ic = 0; ic < 32; ic += 4) {
                const float* i0 = ipb + ic * 360;
                const float* w0 = wb + ic * 25;
                #pragma unroll
                for (int ky = 0; ky < 5; ++ky)
                    #pragma unroll
                    for (int kx = 0; kx < 5; ++kx) {
                        c0 = fmaf(i0[ky * 20 + kx],        w0[ky * 5 + kx],      c0);
                        c1 = fmaf(i0[360 + ky * 20 + kx],  w0[25 + ky * 5 + kx], c1);
                        c2 = fmaf(i0[720 + ky * 20 + kx],  w0[50 + ky * 5 + kx], c2);
                        c3 = fmaf(i0[1080 + ky * 20 + kx], w0[75 + ky * 5 + kx], c3);
                    }
            }
            c = (c0 + c1) + (c2 + c3);
        }
        size_t gi = (size_t)bo * 196 + tid;
        float um_ = fmaf(um[gi], DM, c);
        float us_ = fmaf(us[gi], DS, c);
        float sv = sav[gi];
        float u = sv * (um_ - us_);
        s = (u > 1.0f) ? 1.f : 0.f;
        um[gi] = um_; us[gi] = us_; sav[gi] = sv * (1.f - s);
        float te_ = te[gi];
        te_ += ((te_ != 0.f) || (um_ != 0.f)) ? 1.f : 0.f;
        te[gi] = te_;
        float lt = lat[gi] + s * (te_ - 15.f);
        lat[gi] = lt;
        s_sp[tid] = s; s_lat[tid] = lt;
    }
    spike_count_add(tid < 196 ? s : 0.f, red, &ssp[2]);  // barrier inside
    if (tid < 49) {
        int py = tid / 7, px = tid - py * 7;
        int base = (2 * py) * 14 + 2 * px;
        float s00 = s_sp[base],      l00 = s_lat[base];
        float s01 = s_sp[base + 1],  l01 = s_lat[base + 1];
        float s10 = s_sp[base + 14], l10 = s_lat[base + 14];
        float s11 = s_sp[base + 15], l11 = s_lat[base + 15];
        float lmin = fminf(fminf(l00, l01), fminf(l10, l11));
        float o = fmaxf(fmaxf(l00 == lmin ? s00 : 0.f, l01 == lmin ? s01 : 0.f),
                        fmaxf(l10 == lmin ? s10 : 0.f, l11 == lmin ? s11 : 0.f));
        p2[(size_t)b * 3136 + oc * 49 + tid] = o;
    }
}

// fc1: sparse gather over spiking inputs (deterministic ballot compaction) + NOSO
__launch_bounds__(640)
__global__ void k_fc1(const float* __restrict__ wt, const float* __restrict__ p2,
                      float* __restrict__ um, float* __restrict__ us,
                      float* __restrict__ sav, float* __restrict__ sp,
                      float* __restrict__ ssp) {
    __shared__ float s_s[3136];
    __shared__ int s_idx[3136];
    __shared__ int s_nnz;
    __shared__ float red[16];
    int b = blockIdx.x, tid = threadIdx.x;
    for (int k = tid; k < 3136; k += 640) s_s[k] = p2[(size_t)b * 3136 + k];
    __syncthreads();
    if (tid < 64) {
        int count = 0;
        for (int base = 0; base < 3136; base += 64) {   // 3136 = 49*64
            float v = s_s[base + tid];
            unsigned long long m = __ballot(v != 0.f);
            if (v != 0.f) {
                int pos = count + __popcll(m & ((1ull << tid) - 1ull));
                s_idx[pos] = base + tid;
            }
            count += __popcll(m);
        }
        if (tid == 0) s_nnz = count;
    }
    __syncthreads();
    int nnz = s_nnz;
    float s = 0.f;
    if (tid < 600) {
        float a0 = 0.f, a1 = 0.f, a2 = 0.f, a3 = 0.f;
        int i = 0;
        for (; i + 4 <= nnz; i += 4) {
            a0 += wt[(size_t)s_idx[i]     * 600 + tid];
            a1 += wt[(size_t)s_idx[i + 1] * 600 + tid];
            a2 += wt[(size_t)s_idx[i + 2] * 600 + tid];
            a3 += wt[(size_t)s_idx[i + 3] * 600 + tid];
        }
        for (; i < nnz; ++i) a0 += wt[(size_t)s_idx[i] * 600 + tid];
        float c = (a0 + a1) + (a2 + a3);
        size_t gi = (size_t)b * 600 + tid;
        float um_ = fmaf(um[gi], DM, c);
        float us_ = fmaf(us[gi], DS, c);
        float sv = sav[gi];
        float u = sv * (um_ - us_);
        s = (u > 1.0f) ? 1.f : 0.f;
        um[gi] = um_; us[gi] = us_; sav[gi] = sv * (1.f - s);
        sp[gi] = s;
    }
    spike_count_add(tid < 600 ? s : 0.f, red, &ssp[3]);
}

// fc2 (output layer): NOSO + t_elapse/out_t/out_u + zero nnz counters for next step
__launch_bounds__(640)
__global__ void k_fc2(const float* __restrict__ wf2, const float* __restrict__ sp1,
                      float* __restrict__ um, float* __restrict__ us,
                      float* __restrict__ sav, float* __restrict__ outt,
                      float* __restrict__ outu, float* __restrict__ tel,
                      float* __restrict__ nnzbuf, float* __restrict__ ssp) {
    __shared__ float red[16];
    int idx = blockIdx.x * 640 + threadIdx.x;   // 2*640 = 1280 exact
    int b = idx / 10, j = idx - b * 10;
    const float* ip = sp1 + (size_t)b * 600;
    const float* w = wf2 + j * 600;
    float a0 = 0.f, a1 = 0.f, a2 = 0.f, a3 = 0.f;
    for (int k = 0; k < 600; k += 4) {
        a0 = fmaf(ip[k],     w[k],     a0);
        a1 = fmaf(ip[k + 1], w[k + 1], a1);
        a2 = fmaf(ip[k + 2], w[k + 2], a2);
        a3 = fmaf(ip[k + 3], w[k + 3], a3);
    }
    float c = (a0 + a1) + (a2 + a3);
    float um_ = fmaf(um[idx], DM, c);
    float us_ = fmaf(us[idx], DS, c);
    float sv = sav[idx];
    float u = sv * (um_ - us_);
    float s = (u > 1.0f) ? 1.f : 0.f;
    um[idx] = um_; us[idx] = us_; sav[idx] = sv * (1.f - s);
    float tl = tel[idx];
    tl += ((tl != 0.f) || (u != 0.f)) ? 1.f : 0.f;
    tel[idx] = tl;
    outt[idx] += s * (tl - 16.f);
    outu[idx] += s * u;
    if (blockIdx.x == 0 && threadIdx.x < 256) nnzbuf[threadIdx.x] = 0.f;
    spike_count_add(s, red, &ssp[4]);
}

__global__ void k_out(const float* __restrict__ outt, const float* __restrict__ outu,
                      const float* __restrict__ ssp, float* __restrict__ out) {
    int i = blockIdx.x * 256 + threadIdx.x;
    if (i < 1280)       out[i] = outt[i];
    else if (i < 2560)  out[i] = outu[i - 1280];
    else if (i < 2565)  out[i] = ssp[i - 2560];
}

// ---------------- launch ----------------
extern "C" void kernel_launch(void* const* d_in, const int* in_sizes, int n_in,
                              void* d_out, int out_size, void* d_ws, size_t ws_size,
                              hipStream_t stream) {
    (void)in_sizes; (void)n_in; (void)out_size;
    if (ws_size < TOTALF * sizeof(float)) return;  // need ~114 MB scratch

    const float* inp = (const float*)d_in[0];
    const float* w1  = (const float*)d_in[1];
    const float* w2  = (const float*)d_in[2];
    const float* wf1 = (const float*)d_in[3];
    const float* wf2 = (const float*)d_in[4];
    float* ws  = (float*)d_ws;
    float* out = (float*)d_out;

    // init state (every launch: harness does not re-poison / we must be deterministic)
    k_fill<<<2048, 256, 0, stream>>>(ws, TOTALF, 0.f);
    k_fill<<<1024, 256, 0, stream>>>(ws + o_sav1, N_C1, 1.f);
    k_fill<<<1024, 256, 0, stream>>>(ws + o_lat1, N_C1, 16.f);
    k_fill<<<512, 256, 0, stream>>>(ws + o_sav2, N_C2, 1.f);
    k_fill<<<512, 256, 0, stream>>>(ws + o_lat2, N_C2, 16.f);
    k_fill<<<38, 256, 0, stream>>>(ws + o_f1sv, N_F1, 1.f);
    k_fill<<<5, 256, 0, stream>>>(ws + o_f2sv, N_F2, 1.f);
    k_fill<<<5, 256, 0, stream>>>(ws + o_outt, N_F2, 16.f);
    k_transpose<<<(600 * 3136 + 255) / 256, 256, 0, stream>>>(wf1, ws + o_wt);

    for (int t = 0; t < 16; ++t) {
        k_input<<<N_IN / 256, 256, 0, stream>>>(inp, ws + o_inu, ws + o_insp,
                                                ws + o_nnz, ws + o_ssp);
        k_conv1<<<BATCH * 32, 832, 0, stream>>>(w1, ws + o_insp, ws + o_um1, ws + o_us1,
                                                ws + o_sav1, ws + o_te1, ws + o_lat1,
                                                ws + o_p1p, ws + o_nnz, ws + o_nnz + 128,
                                                ws + o_ssp);
        k_conv2<<<BATCH * 64, 256, 0, stream>>>(w2, ws + o_p1p, ws + o_um2, ws + o_us2,
                                                ws + o_sav2, ws + o_te2, ws + o_lat2,
                                                ws + o_p2, ws + o_nnz + 128, ws + o_ssp);
        k_fc1<<<BATCH, 640, 0, stream>>>(ws + o_wt, ws + o_p2, ws + o_f1um, ws + o_f1us,
                                         ws + o_f1sv, ws + o_f1sp, ws + o_ssp);
        k_fc2<<<2, 640, 0, stream>>>(wf2, ws + o_f1sp, ws + o_f2um, ws + o_f2us,
                                     ws + o_f2sv, ws + o_outt, ws + o_outu, ws + o_tel,
                                     ws + o_nnz, ws + o_ssp);
    }
    k_out<<<11, 256, 0, stream>>>(ws + o_outt, ws + o_outu, ws + o_ssp, out);
}

// Round 2
// 1402.604 us; speedup vs baseline: 1.4720x; 1.4720x over previous
//
#include <hip/hip_runtime.h>

#define BATCH 128

constexpr float DM = 0.95122942450071400910f;  // exp(-1/20)
constexpr float DS = 0.81873075307798185867f;  // exp(-1/5)

// ---------------- sizes ----------------
constexpr int N_IN  = BATCH * 784;          // input_u (one buffer)
constexpr int N_C1  = BATCH * 32 * 784;     // conv1 neuron state
constexpr int N_P1P = BATCH * 32 * 360;     // padded pooled conv1 spikes (18x20)
constexpr int N_C2  = BATCH * 64 * 196;     // conv2 neuron state
constexpr int N_P2  = BATCH * 3136;         // pooled conv2 spikes, flattened
constexpr int N_F1  = BATCH * 600;
constexpr int N_F2  = BATCH * 10;
constexpr int N_WT  = 3136 * 600;           // transposed fc1 weights

// ---------------- workspace offsets (floats) ----------------
constexpr size_t o_inu  = 0;                // double-buffered: [2][N_IN]
constexpr size_t o_um1  = o_inu  + 2 * N_IN;
constexpr size_t o_us1  = o_um1  + N_C1;
constexpr size_t o_sav1 = o_us1  + N_C1;
constexpr size_t o_te1  = o_sav1 + N_C1;
constexpr size_t o_lat1 = o_te1  + N_C1;
constexpr size_t o_p1p  = o_lat1 + N_C1;
constexpr size_t o_um2  = o_p1p  + N_P1P;
constexpr size_t o_us2  = o_um2  + N_C2;
constexpr size_t o_sav2 = o_us2  + N_C2;
constexpr size_t o_te2  = o_sav2 + N_C2;
constexpr size_t o_lat2 = o_te2  + N_C2;
constexpr size_t o_p2   = o_lat2 + N_C2;
constexpr size_t o_f1um = o_p2   + N_P2;
constexpr size_t o_f1us = o_f1um + N_F1;
constexpr size_t o_f1sv = o_f1us + N_F1;
constexpr size_t o_f2um = o_f1sv + N_F1;
constexpr size_t o_f2us = o_f2um + N_F2;
constexpr size_t o_f2sv = o_f2us + N_F2;
constexpr size_t o_outt = o_f2sv + N_F2;
constexpr size_t o_outu = o_outt + N_F2;
constexpr size_t o_tel  = o_outu + N_F2;
constexpr size_t o_nnz1 = o_tel  + N_F2;    // [128] pooled-conv1 any-spike counts
constexpr size_t o_ssp  = o_nnz1 + 128;     // 8 (5 used)
constexpr size_t o_wt   = o_ssp  + 8;
constexpr size_t TOTALF = o_wt   + N_WT;

// ---------------- helpers ----------------
// block-wide sum of v -> one atomicAdd to dst. Trailing barrier so red[] is reusable.
__device__ __forceinline__ void block_sum_atomic(float v, float* red, float* dst) {
    int lane = threadIdx.x & 63;
    int wid  = threadIdx.x >> 6;
    #pragma unroll
    for (int o = 32; o; o >>= 1) v += __shfl_down(v, o, 64);
    if (lane == 0) red[wid] = v;
    __syncthreads();
    if (threadIdx.x == 0) {
        int nw = ((int)blockDim.x + 63) >> 6;
        float t = 0.f;
        for (int w = 0; w < nw; ++w) t += red[w];
        if (t != 0.f) atomicAdd(dst, t);
    }
    __syncthreads();
}

__global__ void k_fill(float* p, size_t n, float v) {
    size_t i = (size_t)blockIdx.x * blockDim.x + threadIdx.x;
    size_t st = (size_t)gridDim.x * blockDim.x;
    for (; i < n; i += st) p[i] = v;
}

__global__ void k_transpose(const float* __restrict__ w, float* __restrict__ wt) {
    int i = blockIdx.x * 256 + threadIdx.x;
    if (i < 600 * 3136) {
        int j = i / 3136, k = i - j * 3136;
        wt[(size_t)k * 600 + j] = w[i];
    }
}

// ---------------- step kernels ----------------
// fused: input encoding (recomputed per block, state written by oc==0 block)
// + conv1 (1->32, 5x5 pad2, LDS input) + NOSO + te/lat + 2x2 latency min-pool
__launch_bounds__(832)
__global__ void k_conv1(const float* __restrict__ inp, const float* __restrict__ w1,
                        const float* __restrict__ inuA, float* __restrict__ inuB,
                        float* __restrict__ um, float* __restrict__ us,
                        float* __restrict__ sav, float* __restrict__ te,
                        float* __restrict__ lat, float* __restrict__ p1p,
                        float* __restrict__ nnz1, float* __restrict__ ssp) {
    __shared__ float s_in[1024];            // padded 32x32 input spikes
    __shared__ float s_sp[784], s_lat[784];
    __shared__ float red[16];
    __shared__ int anyflag;
    int bo = blockIdx.x;                    // b*32 + oc
    int b = bo >> 5, oc = bo & 31;
    int tid = threadIdx.x;

    for (int k = tid; k < 1024; k += 832) s_in[k] = 0.f;
    if (tid == 0) anyflag = 0;
    __syncthreads();

    float isp = 0.f;
    if (tid < 784) {
        float up = inuA[b * 784 + tid];
        // in_spike(prev) == (up > 1); recompute instead of storing it
        float u = up * DM * (up > 1.0f ? 0.f : 1.f) + inp[b * 784 + tid] * 0.3f;
        isp = (u > 1.0f) ? 1.f : 0.f;
        if (oc == 0) inuB[b * 784 + tid] = u;
        int y = tid / 28, x = tid - y * 28;
        s_in[(y + 2) * 32 + (x + 2)] = isp;
    }
    if (__any(isp != 0.f) && (tid & 63) == 0) anyflag = 1;
    __syncthreads();
    if (oc == 0) block_sum_atomic(isp, red, &ssp[0]);   // block-uniform branch

    float s = 0.f;
    if (tid < 784) {
        float c = 0.f;
        if (anyflag) {
            int y = tid / 28, x = tid - y * 28;
            const float* ip = &s_in[y * 32 + x];
            const float* w = w1 + oc * 25;
            #pragma unroll
            for (int ky = 0; ky < 5; ++ky)
                #pragma unroll
                for (int kx = 0; kx < 5; ++kx)
                    c = fmaf(ip[ky * 32 + kx], w[ky * 5 + kx], c);
        }
        size_t gi = (size_t)bo * 784 + tid;
        float um_ = fmaf(um[gi], DM, c);
        float us_ = fmaf(us[gi], DS, c);
        float sv = sav[gi];
        float u = sv * (um_ - us_);
        s = (u > 1.0f) ? 1.f : 0.f;
        um[gi] = um_; us[gi] = us_; sav[gi] = sv * (1.f - s);
        float te_ = te[gi];
        te_ += ((te_ != 0.f) || (um_ != 0.f)) ? 1.f : 0.f;
        te[gi] = te_;
        float lt = lat[gi] + s * (te_ - 15.f);
        lat[gi] = lt;
        s_sp[tid] = s; s_lat[tid] = lt;
    }
    block_sum_atomic(tid < 784 ? s : 0.f, red, &ssp[1]);  // barrier covers s_sp/s_lat

    float o = 0.f;
    if (tid < 196) {
        int py = tid / 14, px = tid - py * 14;
        int base = (2 * py) * 28 + 2 * px;
        float s00 = s_sp[base],      l00 = s_lat[base];
        float s01 = s_sp[base + 1],  l01 = s_lat[base + 1];
        float s10 = s_sp[base + 28], l10 = s_lat[base + 28];
        float s11 = s_sp[base + 29], l11 = s_lat[base + 29];
        float lmin = fminf(fminf(l00, l01), fminf(l10, l11));
        o = fmaxf(fmaxf(l00 == lmin ? s00 : 0.f, l01 == lmin ? s01 : 0.f),
                  fmaxf(l10 == lmin ? s10 : 0.f, l11 == lmin ? s11 : 0.f));
        p1p[(size_t)bo * 360 + (py + 2) * 20 + (px + 2)] = o;
    }
    block_sum_atomic((tid < 196 && o != 0.f) ? 1.f : 0.f, red, &nnz1[b]);
}

// conv2 (32->64, 5x5 pad2) + NOSO + te/lat + fused pool -> flattened fc1 input
__launch_bounds__(256)
__global__ void k_conv2(const float* __restrict__ w2, const float* __restrict__ p1p,
                        float* __restrict__ um, float* __restrict__ us,
                        float* __restrict__ sav, float* __restrict__ te,
                        float* __restrict__ lat, float* __restrict__ p2,
                        const float* __restrict__ nnz1, float* __restrict__ ssp) {
    __shared__ float s_sp[196], s_lat[196], red[16];
    int bo = blockIdx.x;              // b*64 + oc
    int b = bo >> 6, oc = bo & 63;
    int tid = threadIdx.x;
    float s = 0.f;
    if (tid < 196) {
        int y = tid / 14, x = tid - y * 14;
        float c = 0.f;
        if (nnz1[b] != 0.f) {
            const float* ipb = p1p + (size_t)b * (32 * 360) + y * 20 + x;
            const float* wb = w2 + oc * 800;
            float c0 = 0.f, c1 = 0.f, c2 = 0.f, c3 = 0.f;
            for (int ic = 0; ic < 32; ic += 4) {
                const float* i0 = ipb + ic * 360;
                const float* w0 = wb + ic * 25;
                #pragma unroll
                for (int ky = 0; ky < 5; ++ky)
                    #pragma unroll
                    for (int kx = 0; kx < 5; ++kx) {
                        c0 = fmaf(i0[ky * 20 + kx],        w0[ky * 5 + kx],      c0);
                        c1 = fmaf(i0[360 + ky * 20 + kx],  w0[25 + ky * 5 + kx], c1);
                        c2 = fmaf(i0[720 + ky * 20 + kx],  w0[50 + ky * 5 + kx], c2);
                        c3 = fmaf(i0[1080 + ky * 20 + kx], w0[75 + ky * 5 + kx], c3);
                    }
            }
            c = (c0 + c1) + (c2 + c3);
        }
        size_t gi = (size_t)bo * 196 + tid;
        float um_ = fmaf(um[gi], DM, c);
        float us_ = fmaf(us[gi], DS, c);
        float sv = sav[gi];
        float u = sv * (um_ - us_);
        s = (u > 1.0f) ? 1.f : 0.f;
        um[gi] = um_; us[gi] = us_; sav[gi] = sv * (1.f - s);
        float te_ = te[gi];
        te_ += ((te_ != 0.f) || (um_ != 0.f)) ? 1.f : 0.f;
        te[gi] = te_;
        float lt = lat[gi] + s * (te_ - 15.f);
        lat[gi] = lt;
        s_sp[tid] = s; s_lat[tid] = lt;
    }
    block_sum_atomic(tid < 196 ? s : 0.f, red, &ssp[2]);  // barrier covers s_sp/s_lat
    if (tid < 49) {
        int py = tid / 7, px = tid - py * 7;
        int base = (2 * py) * 14 + 2 * px;
        float s00 = s_sp[base],      l00 = s_lat[base];
        float s01 = s_sp[base + 1],  l01 = s_lat[base + 1];
        float s10 = s_sp[base + 14], l10 = s_lat[base + 14];
        float s11 = s_sp[base + 15], l11 = s_lat[base + 15];
        float lmin = fminf(fminf(l00, l01), fminf(l10, l11));
        float o = fmaxf(fmaxf(l00 == lmin ? s00 : 0.f, l01 == lmin ? s01 : 0.f),
                        fmaxf(l10 == lmin ? s10 : 0.f, l11 == lmin ? s11 : 0.f));
        p2[(size_t)b * 3136 + oc * 49 + tid] = o;
    }
}

// fused fc1 (sparse gather, ballot compaction) + fc2 output layer
__launch_bounds__(640)
__global__ void k_fc12(const float* __restrict__ wt, const float* __restrict__ p2,
                       const float* __restrict__ wf2,
                       float* __restrict__ f1um, float* __restrict__ f1us,
                       float* __restrict__ f1sv,
                       float* __restrict__ f2um, float* __restrict__ f2us,
                       float* __restrict__ f2sv,
                       float* __restrict__ outt, float* __restrict__ outu,
                       float* __restrict__ tel,
                       float* __restrict__ nnz1, float* __restrict__ ssp) {
    __shared__ float s_s[3136];
    __shared__ int s_idx[3136];
    __shared__ int s_nnz;
    __shared__ float red[16];
    __shared__ float s_sp1[600];
    __shared__ float s_f2[10];
    int b = blockIdx.x, tid = threadIdx.x;
    for (int k = tid; k < 3136; k += 640) s_s[k] = p2[(size_t)b * 3136 + k];
    __syncthreads();
    if (tid < 64) {
        int count = 0;
        for (int base = 0; base < 3136; base += 64) {   // 3136 = 49*64
            float v = s_s[base + tid];
            unsigned long long m = __ballot(v != 0.f);
            if (v != 0.f) {
                int pos = count + __popcll(m & ((1ull << tid) - 1ull));
                s_idx[pos] = base + tid;
            }
            count += __popcll(m);
        }
        if (tid == 0) s_nnz = count;
    }
    __syncthreads();
    int nnz = s_nnz;
    float s = 0.f;
    if (tid < 600) {
        float a0 = 0.f, a1 = 0.f, a2 = 0.f, a3 = 0.f;
        int i = 0;
        for (; i + 4 <= nnz; i += 4) {
            a0 += wt[(size_t)s_idx[i]     * 600 + tid];
            a1 += wt[(size_t)s_idx[i + 1] * 600 + tid];
            a2 += wt[(size_t)s_idx[i + 2] * 600 + tid];
            a3 += wt[(size_t)s_idx[i + 3] * 600 + tid];
        }
        for (; i < nnz; ++i) a0 += wt[(size_t)s_idx[i] * 600 + tid];
        float c = (a0 + a1) + (a2 + a3);
        size_t gi = (size_t)b * 600 + tid;
        float um_ = fmaf(f1um[gi], DM, c);
        float us_ = fmaf(f1us[gi], DS, c);
        float sv = f1sv[gi];
        float u = sv * (um_ - us_);
        s = (u > 1.0f) ? 1.f : 0.f;
        f1um[gi] = um_; f1us[gi] = us_; f1sv[gi] = sv * (1.f - s);
        s_sp1[tid] = s;
    }
    if (b == 0 && tid < 128) nnz1[tid] = 0.f;     // reset gate counters for next step
    block_sum_atomic(tid < 600 ? s : 0.f, red, &ssp[3]);  // barrier covers s_sp1

    // fc2: wave w handles output neuron j=w (10 waves)
    int w = tid >> 6, lane = tid & 63;
    const float* wrow = wf2 + w * 600;
    float a = 0.f;
    #pragma unroll
    for (int i = 0; i < 10; ++i) {
        int k = lane + i * 64;
        if (k < 600) a = fmaf(s_sp1[k], wrow[k], a);
    }
    #pragma unroll
    for (int o = 32; o; o >>= 1) a += __shfl_down(a, o, 64);
    if (lane == 0) {
        int idx = b * 10 + w;
        float um_ = fmaf(f2um[idx], DM, a);
        float us_ = fmaf(f2us[idx], DS, a);
        float sv = f2sv[idx];
        float u = sv * (um_ - us_);
        float s2 = (u > 1.0f) ? 1.f : 0.f;
        f2um[idx] = um_; f2us[idx] = us_; f2sv[idx] = sv * (1.f - s2);
        float tl = tel[idx];
        tl += ((tl != 0.f) || (u != 0.f)) ? 1.f : 0.f;
        tel[idx] = tl;
        outt[idx] += s2 * (tl - 16.f);
        outu[idx] += s2 * u;
        s_f2[w] = s2;
    }
    __syncthreads();
    if (tid == 0) {
        float t = 0.f;
        for (int j = 0; j < 10; ++j) t += s_f2[j];
        if (t != 0.f) atomicAdd(&ssp[4], t);
    }
}

__global__ void k_out(const float* __restrict__ outt, const float* __restrict__ outu,
                      const float* __restrict__ ssp, float* __restrict__ out) {
    int i = blockIdx.x * 256 + threadIdx.x;
    if (i < 1280)       out[i] = outt[i];
    else if (i < 2560)  out[i] = outu[i - 1280];
    else if (i < 2565)  out[i] = ssp[i - 2560];
}

// ---------------- launch ----------------
extern "C" void kernel_launch(void* const* d_in, const int* in_sizes, int n_in,
                              void* d_out, int out_size, void* d_ws, size_t ws_size,
                              hipStream_t stream) {
    (void)in_sizes; (void)n_in; (void)out_size;
    if (ws_size < TOTALF * sizeof(float)) return;

    const float* inp = (const float*)d_in[0];
    const float* w1  = (const float*)d_in[1];
    const float* w2  = (const float*)d_in[2];
    const float* wf1 = (const float*)d_in[3];
    const float* wf2 = (const float*)d_in[4];
    float* ws  = (float*)d_ws;
    float* out = (float*)d_out;

    // init state (every launch; deterministic)
    k_fill<<<2048, 256, 0, stream>>>(ws, TOTALF, 0.f);
    k_fill<<<1024, 256, 0, stream>>>(ws + o_sav1, N_C1, 1.f);
    k_fill<<<1024, 256, 0, stream>>>(ws + o_lat1, N_C1, 16.f);
    k_fill<<<512, 256, 0, stream>>>(ws + o_sav2, N_C2, 1.f);
    k_fill<<<512, 256, 0, stream>>>(ws + o_lat2, N_C2, 16.f);
    k_fill<<<38, 256, 0, stream>>>(ws + o_f1sv, N_F1, 1.f);
    k_fill<<<5, 256, 0, stream>>>(ws + o_f2sv, N_F2, 1.f);
    k_fill<<<5, 256, 0, stream>>>(ws + o_outt, N_F2, 16.f);
    k_transpose<<<(600 * 3136 + 255) / 256, 256, 0, stream>>>(wf1, ws + o_wt);

    for (int t = 0; t < 16; ++t) {
        const float* inuA = ws + o_inu + (t & 1) * N_IN;
        float* inuB = ws + o_inu + ((t + 1) & 1) * N_IN;
        k_conv1<<<BATCH * 32, 832, 0, stream>>>(inp, w1, inuA, inuB,
                                                ws + o_um1, ws + o_us1, ws + o_sav1,
                                                ws + o_te1, ws + o_lat1, ws + o_p1p,
                                                ws + o_nnz1, ws + o_ssp);
        k_conv2<<<BATCH * 64, 256, 0, stream>>>(w2, ws + o_p1p, ws + o_um2, ws + o_us2,
                                                ws + o_sav2, ws + o_te2, ws + o_lat2,
                                                ws + o_p2, ws + o_nnz1, ws + o_ssp);
        k_fc12<<<BATCH, 640, 0, stream>>>(ws + o_wt, ws + o_p2, wf2,
                                          ws + o_f1um, ws + o_f1us, ws + o_f1sv,
                                          ws + o_f2um, ws + o_f2us, ws + o_f2sv,
                                          ws + o_outt, ws + o_outu, ws + o_tel,
                                          ws + o_nnz1, ws + o_ssp);
    }
    k_out<<<11, 256, 0, stream>>>(ws + o_outt, ws + o_outu, ws + o_ssp, out);
}

// Round 3
// 450.503 us; speedup vs baseline: 4.5829x; 3.1134x over previous
//
#include <hip/hip_runtime.h>

#define BATCH 128

constexpr float DM = 0.95122942450071400910f;  // exp(-1/20)
constexpr float DS = 0.81873075307798185867f;  // exp(-1/5)

// ---------------- workspace layout (float units) ----------------
constexpr size_t o_wt   = 0;                              // [3136][600] f32 (fc1 transposed)
constexpr size_t o_p1p  = o_wt + (size_t)3136 * 600;      // [16][128*32][360] f32 padded pooled conv1
constexpr size_t o_p2   = o_p1p + (size_t)16 * 4096 * 360;       // [16][128][64] u64 (2 floats each)
constexpr size_t o_flag = o_p2 + (size_t)16 * 128 * 64 * 2;      // [16][128][32] u8
constexpr size_t TOTALF = o_flag + (size_t)(16 * 128 * 32) / 4 + 16;

// ---------------- helpers ----------------
__device__ __forceinline__ void block_sum_atomic(float v, float* red, float* dst) {
    int lane = threadIdx.x & 63;
    int wid  = threadIdx.x >> 6;
    #pragma unroll
    for (int o = 32; o; o >>= 1) v += __shfl_down(v, o, 64);
    if (lane == 0) red[wid] = v;
    __syncthreads();
    if (threadIdx.x == 0) {
        int nw = ((int)blockDim.x + 63) >> 6;
        float t = 0.f;
        for (int w = 0; w < nw; ++w) t += red[w];
        if (t != 0.f) atomicAdd(dst, t);
    }
    __syncthreads();
}

__global__ void k_fill(float* p, size_t n, float v) {
    size_t i = (size_t)blockIdx.x * blockDim.x + threadIdx.x;
    size_t st = (size_t)gridDim.x * blockDim.x;
    for (; i < n; i += st) p[i] = v;
}

// tiled transpose: w[600][3136] -> wt[3136][600]
__global__ void k_transpose(const float* __restrict__ w, float* __restrict__ wt) {
    __shared__ float tile[32][33];
    int k0 = blockIdx.x * 32, j0 = blockIdx.y * 32;
    int lx = threadIdx.x & 31, ly = threadIdx.x >> 5;   // 256 threads = 32x8
    #pragma unroll
    for (int r = 0; r < 32; r += 8) {
        int j = j0 + ly + r, k = k0 + lx;
        tile[ly + r][lx] = (j < 600 && k < 3136) ? w[(size_t)j * 3136 + k] : 0.f;
    }
    __syncthreads();
    #pragma unroll
    for (int r = 0; r < 32; r += 8) {
        int k = k0 + ly + r, j = j0 + lx;
        if (k < 3136 && j < 600) wt[(size_t)k * 600 + j] = tile[lx][ly + r];
    }
}

// ---------------- conv1: all 16 steps fused, state in registers ----------------
// block = (b, oc); input encoding recomputed per block; pooled maps + flags out.
__launch_bounds__(832)
__global__ void k_conv1(const float* __restrict__ inp, const float* __restrict__ w1,
                        float* __restrict__ p1p, unsigned char* __restrict__ flags,
                        float* __restrict__ ssp) {
    __shared__ float s_in[1024];            // padded 32x32 input spikes
    __shared__ float s_sp[784], s_lat[784];
    __shared__ float red[16];
    __shared__ int s_iflag[16];             // any input spike at step t
    __shared__ int s_pf[16];                // any pooled spike at step t
    int bo = blockIdx.x;                    // b*32 + oc
    int b = bo >> 5, oc = bo & 31;
    int tid = threadIdx.x;

    for (int k = tid; k < 1024; k += 832) s_in[k] = 0.f;
    if (tid < 16) { s_iflag[tid] = 0; s_pf[tid] = 0; }

    float x = 0.f; int y = 0, xx = 0;
    if (tid < 784) {
        x = inp[b * 784 + tid] * 0.3f;
        y = tid / 28; xx = tid - y * 28;
    }
    const float* w = w1 + oc * 25;          // uniform -> s_load hoisted
    float uin = 0.f, isp = 0.f;
    float um = 0.f, us = 0.f, sav = 1.f, te = 0.f, lt = 16.f;
    float cnt_in = 0.f, cnt_c1 = 0.f;
    __syncthreads();

    for (int t = 0; t < 16; ++t) {
        // input encode (recomputed by every oc block; registers only)
        if (tid < 784) {
            uin = uin * DM * (1.f - isp) + x;
            isp = (uin > 1.f) ? 1.f : 0.f;
            s_in[(y + 2) * 32 + xx + 2] = isp;
            cnt_in += isp;
        }
        if (__any(isp != 0.f) && (tid & 63) == 0) s_iflag[t] = 1;
        __syncthreads();                    // B1: s_in + iflag ready

        float c = 0.f;
        float s = 0.f;
        if (tid < 784) {
            if (s_iflag[t]) {
                const float* ip = &s_in[y * 32 + xx];
                #pragma unroll
                for (int ky = 0; ky < 5; ++ky)
                    #pragma unroll
                    for (int kx = 0; kx < 5; ++kx)
                        c = fmaf(ip[ky * 32 + kx], w[ky * 5 + kx], c);
            }
            um = fmaf(um, DM, c);
            us = fmaf(us, DS, c);
            float u = sav * (um - us);
            s = (u > 1.f) ? 1.f : 0.f;
            sav *= (1.f - s);
            te += ((te != 0.f) || (um != 0.f)) ? 1.f : 0.f;
            lt += s * (te - 15.f);
            s_sp[tid] = s; s_lat[tid] = lt;
            cnt_c1 += s;
        }
        __syncthreads();                    // B2: s_sp/s_lat ready

        // pooled padded 18x20 write (borders written as 0, no memset needed)
        float anyp = 0.f;
        if (tid < 360) {
            int r = tid / 20, cc = tid - r * 20;
            float o = 0.f;
            if (r >= 2 && r < 16 && cc >= 2 && cc < 16) {
                int py = r - 2, px = cc - 2;
                int base = (2 * py) * 28 + 2 * px;
                float s00 = s_sp[base],      l00 = s_lat[base];
                float s01 = s_sp[base + 1],  l01 = s_lat[base + 1];
                float s10 = s_sp[base + 28], l10 = s_lat[base + 28];
                float s11 = s_sp[base + 29], l11 = s_lat[base + 29];
                float lmin = fminf(fminf(l00, l01), fminf(l10, l11));
                o = fmaxf(fmaxf(l00 == lmin ? s00 : 0.f, l01 == lmin ? s01 : 0.f),
                          fmaxf(l10 == lmin ? s10 : 0.f, l11 == lmin ? s11 : 0.f));
            }
            p1p[((size_t)t * 4096 + bo) * 360 + tid] = o;
            anyp = o;
        }
        if (__any(anyp != 0.f) && (tid & 63) == 0) s_pf[t] = 1;
        __syncthreads();                    // B3: safe to reuse LDS next step
    }

    if (tid < 16)
        flags[((size_t)tid * 128 + b) * 32 + oc] = (unsigned char)s_pf[tid];
    block_sum_atomic(cnt_c1, red, &ssp[1]);
    if (oc == 0) block_sum_atomic(cnt_in, red, &ssp[0]);
}

// ---------------- conv2: all 16 steps fused, state in registers ----------------
// block = (b, oc); dense gather gated by per-(t,b) / per-4ic-group flags.
__launch_bounds__(256)
__global__ void k_conv2(const float* __restrict__ w2, const float* __restrict__ p1p,
                        const unsigned char* __restrict__ flags,
                        unsigned long long* __restrict__ p2, float* __restrict__ ssp) {
    __shared__ float s_sp[196], s_lat[196];
    __shared__ float red[4];
    int bo = blockIdx.x;                    // b*64 + oc
    int b = bo >> 6, oc = bo & 63;
    int tid = threadIdx.x;
    int y = tid / 14, x = tid - y * 14;     // valid for tid<196
    const float* wb = w2 + oc * 800;
    float um = 0.f, us = 0.f, sav = 1.f, te = 0.f, lt = 16.f, cnt = 0.f;

    for (int t = 0; t < 16; ++t) {
        const unsigned* fg = (const unsigned*)(flags + ((size_t)t * 128 + b) * 32);
        unsigned f0 = fg[0], f1 = fg[1], f2 = fg[2], f3 = fg[3];
        unsigned f4 = fg[4], f5 = fg[5], f6 = fg[6], f7 = fg[7];
        bool open = (f0 | f1 | f2 | f3 | f4 | f5 | f6 | f7) != 0;

        float s = 0.f;
        if (tid < 196) {
            float c = 0.f;
            if (open) {
                const float* ipb = p1p + ((size_t)t * 4096 + b * 32) * 360 + y * 20 + x;
                float c0 = 0.f, c1 = 0.f, c2 = 0.f, c3 = 0.f;
                unsigned gfl[8] = {f0, f1, f2, f3, f4, f5, f6, f7};
                #pragma unroll
                for (int g = 0; g < 8; ++g) {
                    if (gfl[g]) {
                        const float* i0 = ipb + (size_t)g * 4 * 360;
                        const float* w0 = wb + g * 100;
                        #pragma unroll
                        for (int ky = 0; ky < 5; ++ky)
                            #pragma unroll
                            for (int kx = 0; kx < 5; ++kx) {
                                c0 = fmaf(i0[ky * 20 + kx],        w0[ky * 5 + kx],      c0);
                                c1 = fmaf(i0[360 + ky * 20 + kx],  w0[25 + ky * 5 + kx], c1);
                                c2 = fmaf(i0[720 + ky * 20 + kx],  w0[50 + ky * 5 + kx], c2);
                                c3 = fmaf(i0[1080 + ky * 20 + kx], w0[75 + ky * 5 + kx], c3);
                            }
                    }
                }
                c = (c0 + c1) + (c2 + c3);
            }
            um = fmaf(um, DM, c);
            us = fmaf(us, DS, c);
            float u = sav * (um - us);
            s = (u > 1.f) ? 1.f : 0.f;
            sav *= (1.f - s);
            te += ((te != 0.f) || (um != 0.f)) ? 1.f : 0.f;
            lt += s * (te - 15.f);
            s_sp[tid] = s; s_lat[tid] = lt;
            cnt += s;
        }
        __syncthreads();                    // s_sp/s_lat ready

        float o = 0.f;
        if (tid < 49) {
            int py = tid / 7, px = tid - py * 7;
            int base = (2 * py) * 14 + 2 * px;
            float s00 = s_sp[base],      l00 = s_lat[base];
            float s01 = s_sp[base + 1],  l01 = s_lat[base + 1];
            float s10 = s_sp[base + 14], l10 = s_lat[base + 14];
            float s11 = s_sp[base + 15], l11 = s_lat[base + 15];
            float lmin = fminf(fminf(l00, l01), fminf(l10, l11));
            o = fmaxf(fmaxf(l00 == lmin ? s00 : 0.f, l01 == lmin ? s01 : 0.f),
                      fmaxf(l10 == lmin ? s10 : 0.f, l11 == lmin ? s11 : 0.f));
        }
        if (tid < 64) {
            unsigned long long m = __ballot(o != 0.f);
            if (tid == 0) p2[((size_t)t * 128 + b) * 64 + oc] = m;
        }
        __syncthreads();                    // safe to reuse LDS next step
    }
    block_sum_atomic(cnt, red, &ssp[2]);
}

// ---------------- fc1 + fc2: all 16 steps fused, state in registers ----------------
__launch_bounds__(640)
__global__ void k_fc12(const float* __restrict__ wt, const unsigned long long* __restrict__ p2,
                       const float* __restrict__ wf2, float* __restrict__ out) {
    __shared__ unsigned long long words[64];
    __shared__ int s_idx[3136];
    __shared__ int s_nnz;
    __shared__ float s_sp1[600];
    __shared__ float red[16];
    __shared__ float s_c2[10];
    int b = blockIdx.x, tid = threadIdx.x;
    int w = tid >> 6, lane = tid & 63;
    const float* wrow = wf2 + w * 600;

    float f1um = 0.f, f1us = 0.f, f1sv = 1.f, cnt1 = 0.f;
    float f2um = 0.f, f2us = 0.f, f2sv = 1.f;
    float tel = 0.f, ot = 16.f, ou = 0.f, cnt2 = 0.f;

    for (int t = 0; t < 16; ++t) {
        if (tid < 64) words[tid] = p2[((size_t)t * 128 + b) * 64 + tid];
        __syncthreads();                    // words ready

        if (tid < 64) {
            int count = 0;
            for (int o = 0; o < 64; ++o) {  // ascending (oc, pos): deterministic
                unsigned long long m = words[o];
                if ((m >> tid) & 1ull)
                    s_idx[count + __popcll(m & ((1ull << tid) - 1ull))] = o * 49 + tid;
                count += __popcll(m);
            }
            if (tid == 0) s_nnz = count;
        }
        __syncthreads();                    // s_idx ready
        int nnz = s_nnz;

        float s = 0.f;
        if (tid < 600) {
            float a0 = 0.f, a1 = 0.f, a2 = 0.f, a3 = 0.f;
            int i = 0;
            for (; i + 4 <= nnz; i += 4) {
                a0 += wt[(size_t)s_idx[i]     * 600 + tid];
                a1 += wt[(size_t)s_idx[i + 1] * 600 + tid];
                a2 += wt[(size_t)s_idx[i + 2] * 600 + tid];
                a3 += wt[(size_t)s_idx[i + 3] * 600 + tid];
            }
            for (; i < nnz; ++i) a0 += wt[(size_t)s_idx[i] * 600 + tid];
            float c = (a0 + a1) + (a2 + a3);
            f1um = fmaf(f1um, DM, c);
            f1us = fmaf(f1us, DS, c);
            float u = f1sv * (f1um - f1us);
            s = (u > 1.f) ? 1.f : 0.f;
            f1sv *= (1.f - s);
            s_sp1[tid] = s;
            cnt1 += s;
        }
        __syncthreads();                    // s_sp1 ready

        // fc2: wave w -> output neuron j=w
        float a = 0.f;
        #pragma unroll
        for (int i2 = 0; i2 < 10; ++i2) {
            int k = lane + i2 * 64;
            if (k < 600) a = fmaf(s_sp1[k], wrow[k], a);
        }
        #pragma unroll
        for (int o = 32; o; o >>= 1) a += __shfl_down(a, o, 64);
        if (lane == 0) {
            f2um = fmaf(f2um, DM, a);
            f2us = fmaf(f2us, DS, a);
            float u = f2sv * (f2um - f2us);
            float s2 = (u > 1.f) ? 1.f : 0.f;
            f2sv *= (1.f - s2);
            tel += ((tel != 0.f) || (u != 0.f)) ? 1.f : 0.f;
            ot += s2 * (tel - 16.f);
            ou += s2 * u;
            cnt2 += s2;
        }
        __syncthreads();                    // protect words/s_idx/s_sp1 reuse
    }

    if (lane == 0) {
        out[b * 10 + w] = ot;
        out[1280 + b * 10 + w] = ou;
        s_c2[w] = cnt2;
    }
    block_sum_atomic(tid < 600 ? cnt1 : 0.f, red, &out[2563]);
    if (tid == 0) {
        float tt = 0.f;
        for (int j = 0; j < 10; ++j) tt += s_c2[j];
        if (tt != 0.f) atomicAdd(&out[2564], tt);
    }
}

// ---------------- launch ----------------
extern "C" void kernel_launch(void* const* d_in, const int* in_sizes, int n_in,
                              void* d_out, int out_size, void* d_ws, size_t ws_size,
                              hipStream_t stream) {
    (void)in_sizes; (void)n_in; (void)out_size;
    if (ws_size < TOTALF * sizeof(float)) return;  // ~103 MB (< proven 114 MB)

    const float* inp = (const float*)d_in[0];
    const float* w1  = (const float*)d_in[1];
    const float* w2  = (const float*)d_in[2];
    const float* wf1 = (const float*)d_in[3];
    const float* wf2 = (const float*)d_in[4];
    float* ws  = (float*)d_ws;
    float* out = (float*)d_out;

    k_fill<<<3, 256, 0, stream>>>(out, 2565, 0.f);   // ssp atomics need zeros
    k_transpose<<<dim3(98, 19), 256, 0, stream>>>(wf1, ws + o_wt);

    k_conv1<<<BATCH * 32, 832, 0, stream>>>(inp, w1, ws + o_p1p,
                                            (unsigned char*)(ws + o_flag), out + 2560);
    k_conv2<<<BATCH * 64, 256, 0, stream>>>(w2, ws + o_p1p,
                                            (const unsigned char*)(ws + o_flag),
                                            (unsigned long long*)(ws + o_p2), out + 2560);
    k_fc12<<<BATCH, 640, 0, stream>>>(ws + o_wt, (const unsigned long long*)(ws + o_p2),
                                      wf2, out);
}

// Round 4
// 223.011 us; speedup vs baseline: 9.2578x; 2.0201x over previous
//
#include <hip/hip_runtime.h>

#define BATCH 128

constexpr float DM = 0.95122942450071400910f;  // exp(-1/20)
constexpr float DS = 0.81873075307798185867f;  // exp(-1/5)

// ---------------- workspace layout (float/u32 units) ----------------
constexpr size_t o_wt   = 0;                                  // [3136][600] f32
constexpr size_t o_inb  = o_wt  + (size_t)3136 * 600;         // [16][128][32] u32 input row masks (padded rows)
constexpr size_t o_p1b  = o_inb + (size_t)16 * 128 * 32;      // [16][128][32][18] u32 pooled conv1 bit rows
constexpr size_t o_flag = o_p1b + (size_t)16 * 128 * 32 * 18; // [128][32] u16 per-ic activity masks
constexpr size_t o_p2m  = o_flag + 2048;                      // [128][64][49] u16 per-pos activity masks
constexpr size_t TOTALF = o_p2m + 100352 + 16;                // ~12.9 MB

// ---------------- helpers ----------------
__device__ __forceinline__ void block_sum_atomic(float v, float* red, float* dst) {
    int lane = threadIdx.x & 63;
    int wid  = threadIdx.x >> 6;
    #pragma unroll
    for (int o = 32; o; o >>= 1) v += __shfl_down(v, o, 64);
    if (lane == 0) red[wid] = v;
    __syncthreads();
    if (threadIdx.x == 0) {
        int nw = ((int)blockDim.x + 63) >> 6;
        float t = 0.f;
        for (int w = 0; w < nw; ++w) t += red[w];
        if (t != 0.f) atomicAdd(dst, t);
    }
    __syncthreads();
}

__global__ void k_fill(float* p, size_t n, float v) {
    size_t i = (size_t)blockIdx.x * blockDim.x + threadIdx.x;
    size_t st = (size_t)gridDim.x * blockDim.x;
    for (; i < n; i += st) p[i] = v;
}

// tiled transpose: w[600][3136] -> wt[3136][600]
__global__ void k_transpose(const float* __restrict__ w, float* __restrict__ wt) {
    __shared__ float tile[32][33];
    int k0 = blockIdx.x * 32, j0 = blockIdx.y * 32;
    int lx = threadIdx.x & 31, ly = threadIdx.x >> 5;
    #pragma unroll
    for (int r = 0; r < 32; r += 8) {
        int j = j0 + ly + r, k = k0 + lx;
        tile[ly + r][lx] = (j < 600 && k < 3136) ? w[(size_t)j * 3136 + k] : 0.f;
    }
    __syncthreads();
    #pragma unroll
    for (int r = 0; r < 32; r += 8) {
        int k = k0 + ly + r, j = j0 + lx;
        if (k < 3136 && j < 600) wt[(size_t)k * 600 + j] = tile[lx][ly + r];
    }
}

// ---------------- input encoding -> bit rows ----------------
// block = b, 896 threads (wave = 2 rows of padded-32 layout)
__launch_bounds__(896)
__global__ void k_encode(const float* __restrict__ inp, unsigned* __restrict__ inb,
                         float* __restrict__ ssp) {
    __shared__ float red[16];
    int b = blockIdx.x, tid = threadIdx.x;
    int w = tid >> 6, lane = tid & 63;
    int r = lane >> 5, x = lane & 31;
    int y = 2 * w + r;
    float xv = (x < 28) ? inp[b * 784 + y * 28 + x] * 0.3f : 0.f;
    // zero pad rows rr in {0,1,30,31} for all t
    if (tid < 64) {
        int t = tid >> 2, rsel = tid & 3;
        inb[((size_t)t * 128 + b) * 32 + (rsel < 2 ? rsel : 28 + rsel)] = 0u;
    }
    float uin = 0.f, isp = 0.f, cnt = 0.f;
    for (int t = 0; t < 16; ++t) {
        uin = uin * DM * (1.f - isp) + xv;
        isp = (uin > 1.f && x < 28) ? 1.f : 0.f;
        cnt += isp;
        unsigned long long m = __ballot(isp != 0.f);
        if (lane == 0)       inb[((size_t)t * 128 + b) * 32 + (2 * w + 2)] = (unsigned)m;
        else if (lane == 32) inb[((size_t)t * 128 + b) * 32 + (2 * w + 3)] = (unsigned)(m >> 32);
    }
    block_sum_atomic(cnt, red, &ssp[0]);
}

// ---------------- conv1: bit-LUT, barrier-free t-loop ----------------
// block = (b, oc); thread = one 2x2 pool window (4 NOSO neurons in registers)
__launch_bounds__(256)
__global__ void k_conv1(const float* __restrict__ w1, const unsigned* __restrict__ inb,
                        unsigned* __restrict__ p1b, unsigned short* __restrict__ flags,
                        float* __restrict__ ssp) {
    __shared__ float lut[160];        // [ky][32]: pre-summed weight rows
    __shared__ unsigned sib[512];     // [16][32] input bit rows for this b
    __shared__ unsigned wor[4];
    __shared__ float red[4];
    int bo = blockIdx.x, b = bo >> 5, oc = bo & 31;
    int tid = threadIdx.x;
    int px = tid & 15, py = tid >> 4;          // window coords; valid px<14, py<14
    bool pv = (px < 14) && (py < 14);
    int pb = (py < 14) ? 2 * py : 0;           // clamped row base for LDS reads

    // zero rows of this oc's p1b planes (rows 0,1,16,17), all t
    if (tid < 64) {
        int t = tid >> 2, rsel = tid & 3;
        p1b[(((size_t)t * 128 + b) * 32 + oc) * 18 + (rsel < 2 ? rsel : 14 + rsel)] = 0u;
    }
    if (tid < 160) {
        int ky = tid >> 5, m = tid & 31;
        const float* w = w1 + oc * 25 + ky * 5;
        float v = 0.f;
        #pragma unroll
        for (int kx = 0; kx < 5; ++kx)
            if ((m >> kx) & 1) v += w[kx];
        lut[tid] = v;
    }
    for (int k = tid; k < 512; k += 256)
        sib[k] = inb[((size_t)(k >> 5) * 128 + b) * 32 + (k & 31)];
    if (tid < 4) wor[tid] = 0u;
    __syncthreads();

    float um[2][2] = {}, us[2][2] = {}, te[2][2] = {};
    float sav[2][2] = {{1.f, 1.f}, {1.f, 1.f}};
    float lt[2][2] = {{16.f, 16.f}, {16.f, 16.f}};
    float cnt = 0.f;
    unsigned pm = 0;

    for (int t = 0; t < 16; ++t) {
        unsigned rw[6];
        #pragma unroll
        for (int j = 0; j < 6; ++j) rw[j] = sib[t * 32 + pb + j] << 2;
        unsigned orall = rw[0] | rw[1] | rw[2] | rw[3] | rw[4] | rw[5];

        float c[2][2] = {};
        if (orall) {
            #pragma unroll
            for (int r = 0; r < 2; ++r)
                #pragma unroll
                for (int ky = 0; ky < 5; ++ky) {
                    unsigned wv = rw[r + ky];
                    #pragma unroll
                    for (int cc = 0; cc < 2; ++cc) {
                        unsigned idx = (wv >> (2 * px + cc)) & 31u;
                        c[r][cc] += lut[ky * 32 + idx];
                    }
                }
        }
        float sv[2][2];
        #pragma unroll
        for (int r = 0; r < 2; ++r)
            #pragma unroll
            for (int cc = 0; cc < 2; ++cc) {
                um[r][cc] = fmaf(um[r][cc], DM, c[r][cc]);
                us[r][cc] = fmaf(us[r][cc], DS, c[r][cc]);
                float u = sav[r][cc] * (um[r][cc] - us[r][cc]);
                float s = (u > 1.f) ? 1.f : 0.f;
                sav[r][cc] *= (1.f - s);
                te[r][cc] += ((te[r][cc] != 0.f) || (um[r][cc] != 0.f)) ? 1.f : 0.f;
                lt[r][cc] += s * (te[r][cc] - 15.f);
                sv[r][cc] = s;
                if (pv) cnt += s;
            }
        // in-thread 2x2 latency min-pool
        float lmin = fminf(fminf(lt[0][0], lt[0][1]), fminf(lt[1][0], lt[1][1]));
        float o = fmaxf(fmaxf(lt[0][0] == lmin ? sv[0][0] : 0.f, lt[0][1] == lmin ? sv[0][1] : 0.f),
                        fmaxf(lt[1][0] == lmin ? sv[1][0] : 0.f, lt[1][1] == lmin ? sv[1][1] : 0.f));
        bool hit = (o != 0.f) && pv;
        unsigned long long bal = __ballot(hit);
        int k = tid & 63;
        if (k < 4) {
            int prow = (tid >> 6) * 4 + k;
            if (prow < 14) {
                unsigned wd = (unsigned)(bal >> (k * 16)) & 0x3FFFu;
                p1b[(((size_t)t * 128 + b) * 32 + oc) * 18 + prow + 2] = wd;
            }
        }
        if (hit) pm |= 1u << t;
    }

    unsigned pmw = pm;
    #pragma unroll
    for (int off = 32; off; off >>= 1) pmw |= __shfl_xor(pmw, off, 64);
    if ((tid & 63) == 0) wor[tid >> 6] = pmw;
    block_sum_atomic(cnt, red, &ssp[1]);   // barriers inside make wor visible
    if (tid == 0) flags[b * 32 + oc] = (unsigned short)(wor[0] | wor[1] | wor[2] | wor[3]);
}

// ---------------- conv2: bit-LUT, per-ic gated, zero barriers in t-loop ----------------
// block = (b, oc); thread = one pixel (y,x); pool via shuffles
__launch_bounds__(256)
__global__ void k_conv2(const float* __restrict__ w2, const unsigned* __restrict__ p1b,
                        const unsigned short* __restrict__ flags,
                        unsigned short* __restrict__ p2m, float* __restrict__ ssp) {
    __shared__ float lut[5120];       // [ic*5+ky][32]
    __shared__ float red[4];
    int bo = blockIdx.x, b = bo >> 6, oc = bo & 63;
    int tid = threadIdx.x;
    int x = tid & 15, y = tid >> 4;   // valid x<14, y<14
    bool valid = (x < 14) && (y < 14);
    int yy = valid ? y : 0;

    for (int e = tid; e < 5120; e += 256) {
        int m = e & 31, icky = e >> 5;
        const float* w = w2 + oc * 800 + icky * 5;
        float v = 0.f;
        #pragma unroll
        for (int kx = 0; kx < 5; ++kx)
            if ((m >> kx) & 1) v += w[kx];
        lut[e] = v;
    }
    unsigned fl = flags[b * 32 + (tid & 31)];
    __syncthreads();

    float um = 0.f, us = 0.f, sav = 1.f, te = 0.f, lt = 16.f, cnt = 0.f;
    unsigned pm = 0;
    bool pool_lane = valid && !(x & 1) && !(y & 1);

    for (int t = 0; t < 16; ++t) {
        unsigned actbm = (unsigned)__ballot(((fl >> t) & 1u) && ((tid & 63) < 32));
        float c = 0.f;
        unsigned bm = actbm;
        while (bm) {
            int ic = __builtin_ctz(bm); bm &= bm - 1;
            const unsigned* rp = p1b + (((size_t)t * 128 + b) * 32 + ic) * 18 + yy;
            unsigned r0 = rp[0] << 2, r1 = rp[1] << 2, r2 = rp[2] << 2,
                     r3 = rp[3] << 2, r4 = rp[4] << 2;
            unsigned win = ((r0 | r1 | r2 | r3 | r4) >> x) & 31u;
            if (valid && win) {
                int base = ic * 160;
                c += lut[base +       ((r0 >> x) & 31u)];
                c += lut[base + 32  + ((r1 >> x) & 31u)];
                c += lut[base + 64  + ((r2 >> x) & 31u)];
                c += lut[base + 96  + ((r3 >> x) & 31u)];
                c += lut[base + 128 + ((r4 >> x) & 31u)];
            }
        }
        um = fmaf(um, DM, c);
        us = fmaf(us, DS, c);
        float u = sav * (um - us);
        float s = (u > 1.f) ? 1.f : 0.f;
        sav *= (1.f - s);
        te += ((te != 0.f) || (um != 0.f)) ? 1.f : 0.f;
        lt += s * (te - 15.f);
        if (valid) cnt += s;
        // pool: cols (xor 1), then rows (xor 16)
        float l2 = __shfl_xor(lt, 1, 64), s2 = __shfl_xor(s, 1, 64);
        float lm2 = fminf(lt, l2);
        float o2 = fmaxf(lt == lm2 ? s : 0.f, l2 == lm2 ? s2 : 0.f);
        float l4 = __shfl_xor(lm2, 16, 64), o4 = __shfl_xor(o2, 16, 64);
        float lm4 = fminf(lm2, l4);
        float o = fmaxf(lm2 == lm4 ? o2 : 0.f, l4 == lm4 ? o4 : 0.f);
        if (pool_lane && o != 0.f) pm |= 1u << t;
    }
    if (pool_lane)
        p2m[((size_t)b * 64 + oc) * 49 + (y >> 1) * 7 + (x >> 1)] = (unsigned short)pm;
    block_sum_atomic(cnt, red, &ssp[2]);
}

// ---------------- fc1 + fc2: all steps, state in registers ----------------
__launch_bounds__(640)
__global__ void k_fc12(const float* __restrict__ wt, const unsigned short* __restrict__ p2m,
                       const float* __restrict__ wf2, float* __restrict__ out) {
    __shared__ unsigned short s_m[3136];
    __shared__ int s_idx[3136];
    __shared__ int s_nnz;
    __shared__ float s_sp1[600];
    __shared__ float red[16];
    __shared__ float s_c2[10];
    int b = blockIdx.x, tid = threadIdx.x;
    int w = tid >> 6, lane = tid & 63;
    const float* wrow = wf2 + w * 600;

    for (int k = tid; k < 3136; k += 640) s_m[k] = p2m[(size_t)b * 3136 + k];
    __syncthreads();

    float f1um = 0.f, f1us = 0.f, f1sv = 1.f, cnt1 = 0.f;
    float f2um = 0.f, f2us = 0.f, f2sv = 1.f;
    float tel = 0.f, ot = 16.f, ou = 0.f, cnt2 = 0.f;

    for (int t = 0; t < 16; ++t) {
        if (tid < 64) {
            int count = 0;
            for (int o = 0; o < 64; ++o) {   // ascending (oc, pos): deterministic
                unsigned v = (tid < 49) ? (unsigned)s_m[o * 49 + tid] : 0u;
                unsigned long long m = __ballot((v >> t) & 1u);
                if ((m >> tid) & 1ull)
                    s_idx[count + __popcll(m & ((1ull << tid) - 1ull))] = o * 49 + tid;
                count += __popcll(m);
            }
            if (tid == 0) s_nnz = count;
        }
        __syncthreads();
        int nnz = s_nnz;

        float s = 0.f;
        if (tid < 600) {
            float a0 = 0.f, a1 = 0.f, a2 = 0.f, a3 = 0.f;
            int i = 0;
            for (; i + 4 <= nnz; i += 4) {
                a0 += wt[(size_t)s_idx[i]     * 600 + tid];
                a1 += wt[(size_t)s_idx[i + 1] * 600 + tid];
                a2 += wt[(size_t)s_idx[i + 2] * 600 + tid];
                a3 += wt[(size_t)s_idx[i + 3] * 600 + tid];
            }
            for (; i < nnz; ++i) a0 += wt[(size_t)s_idx[i] * 600 + tid];
            float c = (a0 + a1) + (a2 + a3);
            f1um = fmaf(f1um, DM, c);
            f1us = fmaf(f1us, DS, c);
            float u = f1sv * (f1um - f1us);
            s = (u > 1.f) ? 1.f : 0.f;
            f1sv *= (1.f - s);
            s_sp1[tid] = s;
            cnt1 += s;
        }
        __syncthreads();

        float a = 0.f;
        #pragma unroll
        for (int i2 = 0; i2 < 10; ++i2) {
            int k = lane + i2 * 64;
            if (k < 600) a = fmaf(s_sp1[k], wrow[k], a);
        }
        #pragma unroll
        for (int o = 32; o; o >>= 1) a += __shfl_down(a, o, 64);
        if (lane == 0) {
            f2um = fmaf(f2um, DM, a);
            f2us = fmaf(f2us, DS, a);
            float u = f2sv * (f2um - f2us);
            float s2 = (u > 1.f) ? 1.f : 0.f;
            f2sv *= (1.f - s2);
            tel += ((tel != 0.f) || (u != 0.f)) ? 1.f : 0.f;
            ot += s2 * (tel - 16.f);
            ou += s2 * u;
            cnt2 += s2;
        }
        __syncthreads();
    }

    if (lane == 0) {
        out[b * 10 + w] = ot;
        out[1280 + b * 10 + w] = ou;
        s_c2[w] = cnt2;
    }
    block_sum_atomic(tid < 600 ? cnt1 : 0.f, red, &out[2563]);
    if (tid == 0) {
        float tt = 0.f;
        for (int j = 0; j < 10; ++j) tt += s_c2[j];
        if (tt != 0.f) atomicAdd(&out[2564], tt);
    }
}

// ---------------- launch ----------------
extern "C" void kernel_launch(void* const* d_in, const int* in_sizes, int n_in,
                              void* d_out, int out_size, void* d_ws, size_t ws_size,
                              hipStream_t stream) {
    (void)in_sizes; (void)n_in; (void)out_size;
    if (ws_size < TOTALF * sizeof(float)) return;  // ~13 MB

    const float* inp = (const float*)d_in[0];
    const float* w1  = (const float*)d_in[1];
    const float* w2  = (const float*)d_in[2];
    const float* wf1 = (const float*)d_in[3];
    const float* wf2 = (const float*)d_in[4];
    float* ws  = (float*)d_ws;
    float* out = (float*)d_out;

    k_fill<<<3, 256, 0, stream>>>(out, 2565, 0.f);
    k_transpose<<<dim3(98, 19), 256, 0, stream>>>(wf1, ws + o_wt);

    k_encode<<<BATCH, 896, 0, stream>>>(inp, (unsigned*)(ws + o_inb), out + 2560);
    k_conv1<<<BATCH * 32, 256, 0, stream>>>(w1, (const unsigned*)(ws + o_inb),
                                            (unsigned*)(ws + o_p1b),
                                            (unsigned short*)(ws + o_flag), out + 2560);
    k_conv2<<<BATCH * 64, 256, 0, stream>>>(w2, (const unsigned*)(ws + o_p1b),
                                            (const unsigned short*)(ws + o_flag),
                                            (unsigned short*)(ws + o_p2m), out + 2560);
    k_fc12<<<BATCH, 640, 0, stream>>>(ws + o_wt, (const unsigned short*)(ws + o_p2m),
                                      wf2, out);
}

// Round 5
// 171.928 us; speedup vs baseline: 12.0085x; 1.2971x over previous
//
#include <hip/hip_runtime.h>

#define BATCH 128

constexpr float DM = 0.95122942450071400910f;  // exp(-1/20)
constexpr float DS = 0.81873075307798185867f;  // exp(-1/5)

// ---------------- workspace layout (float units) ----------------
constexpr size_t o_wt   = 0;                                  // [3136][600] f32
constexpr size_t o_inb  = o_wt  + (size_t)3136 * 600;         // [16][128][32] u32 input row masks
constexpr size_t o_p1b  = o_inb + (size_t)16 * 128 * 32;      // [16][128][32][18] u32 pooled conv1 bit rows
constexpr size_t o_flag = o_p1b + (size_t)16 * 128 * 32 * 18; // [128][32] u16 per-ic activity masks
constexpr size_t o_p2m  = o_flag + 2048;                      // [128][64][49] u16 per-pos t-masks (401408 u16)
constexpr size_t o_c1   = o_p2m + 200704;                     // [16][128][600] f32 fc1 pre-activations
constexpr size_t TOTALF = o_c1 + (size_t)16 * 128 * 600 + 16; // ~18 MB

// ---------------- helpers ----------------
__device__ __forceinline__ void block_sum_atomic(float v, float* red, float* dst) {
    int lane = threadIdx.x & 63;
    int wid  = threadIdx.x >> 6;
    #pragma unroll
    for (int o = 32; o; o >>= 1) v += __shfl_down(v, o, 64);
    if (lane == 0) red[wid] = v;
    __syncthreads();
    if (threadIdx.x == 0) {
        int nw = ((int)blockDim.x + 63) >> 6;
        float t = 0.f;
        for (int w = 0; w < nw; ++w) t += red[w];
        if (t != 0.f) atomicAdd(dst, t);
    }
    __syncthreads();
}

__global__ void k_fill(float* p, size_t n, float v) {
    size_t i = (size_t)blockIdx.x * blockDim.x + threadIdx.x;
    size_t st = (size_t)gridDim.x * blockDim.x;
    for (; i < n; i += st) p[i] = v;
}

// tiled transpose: w[600][3136] -> wt[3136][600]
__global__ void k_transpose(const float* __restrict__ w, float* __restrict__ wt) {
    __shared__ float tile[32][33];
    int k0 = blockIdx.x * 32, j0 = blockIdx.y * 32;
    int lx = threadIdx.x & 31, ly = threadIdx.x >> 5;
    #pragma unroll
    for (int r = 0; r < 32; r += 8) {
        int j = j0 + ly + r, k = k0 + lx;
        tile[ly + r][lx] = (j < 600 && k < 3136) ? w[(size_t)j * 3136 + k] : 0.f;
    }
    __syncthreads();
    #pragma unroll
    for (int r = 0; r < 32; r += 8) {
        int k = k0 + ly + r, j = j0 + lx;
        if (k < 3136 && j < 600) wt[(size_t)k * 600 + j] = tile[lx][ly + r];
    }
}

// ---------------- input encoding -> bit rows ----------------
__launch_bounds__(896)
__global__ void k_encode(const float* __restrict__ inp, unsigned* __restrict__ inb,
                         float* __restrict__ ssp) {
    __shared__ float red[16];
    int b = blockIdx.x, tid = threadIdx.x;
    int w = tid >> 6, lane = tid & 63;
    int r = lane >> 5, x = lane & 31;
    int y = 2 * w + r;
    float xv = (x < 28) ? inp[b * 784 + y * 28 + x] * 0.3f : 0.f;
    if (tid < 64) {
        int t = tid >> 2, rsel = tid & 3;
        inb[((size_t)t * 128 + b) * 32 + (rsel < 2 ? rsel : 28 + rsel)] = 0u;
    }
    float uin = 0.f, isp = 0.f, cnt = 0.f;
    for (int t = 0; t < 16; ++t) {
        uin = uin * DM * (1.f - isp) + xv;
        isp = (uin > 1.f && x < 28) ? 1.f : 0.f;
        cnt += isp;
        unsigned long long m = __ballot(isp != 0.f);
        if (lane == 0)       inb[((size_t)t * 128 + b) * 32 + (2 * w + 2)] = (unsigned)m;
        else if (lane == 32) inb[((size_t)t * 128 + b) * 32 + (2 * w + 3)] = (unsigned)(m >> 32);
    }
    block_sum_atomic(cnt, red, &ssp[0]);
}

// ---------------- conv1: bit-LUT, barrier-free t-loop ----------------
__launch_bounds__(256)
__global__ void k_conv1(const float* __restrict__ w1, const unsigned* __restrict__ inb,
                        unsigned* __restrict__ p1b, unsigned short* __restrict__ flags,
                        float* __restrict__ ssp) {
    __shared__ float lut[160];        // [ky][32]: pre-summed weight rows
    __shared__ unsigned sib[512];     // [16][32] input bit rows for this b
    __shared__ unsigned wor[4];
    __shared__ float red[4];
    int bo = blockIdx.x, b = bo >> 5, oc = bo & 31;
    int tid = threadIdx.x;
    int px = tid & 15, py = tid >> 4;
    bool pv = (px < 14) && (py < 14);
    int pb = (py < 14) ? 2 * py : 0;

    if (tid < 64) {
        int t = tid >> 2, rsel = tid & 3;
        p1b[(((size_t)t * 128 + b) * 32 + oc) * 18 + (rsel < 2 ? rsel : 14 + rsel)] = 0u;
    }
    if (tid < 160) {
        int ky = tid >> 5, m = tid & 31;
        const float* w = w1 + oc * 25 + ky * 5;
        float v = 0.f;
        #pragma unroll
        for (int kx = 0; kx < 5; ++kx)
            if ((m >> kx) & 1) v += w[kx];
        lut[tid] = v;
    }
    for (int k = tid; k < 512; k += 256)
        sib[k] = inb[((size_t)(k >> 5) * 128 + b) * 32 + (k & 31)];
    if (tid < 4) wor[tid] = 0u;
    __syncthreads();

    float um[2][2] = {}, us[2][2] = {}, te[2][2] = {};
    float sav[2][2] = {{1.f, 1.f}, {1.f, 1.f}};
    float lt[2][2] = {{16.f, 16.f}, {16.f, 16.f}};
    float cnt = 0.f;
    unsigned pm = 0;

    for (int t = 0; t < 16; ++t) {
        unsigned rw[6];
        #pragma unroll
        for (int j = 0; j < 6; ++j) rw[j] = sib[t * 32 + pb + j] << 2;
        unsigned orall = rw[0] | rw[1] | rw[2] | rw[3] | rw[4] | rw[5];

        float c[2][2] = {};
        if (orall) {
            #pragma unroll
            for (int r = 0; r < 2; ++r)
                #pragma unroll
                for (int ky = 0; ky < 5; ++ky) {
                    unsigned wv = rw[r + ky];
                    #pragma unroll
                    for (int cc = 0; cc < 2; ++cc) {
                        unsigned idx = (wv >> (2 * px + cc)) & 31u;
                        c[r][cc] += lut[ky * 32 + idx];
                    }
                }
        }
        float sv[2][2];
        #pragma unroll
        for (int r = 0; r < 2; ++r)
            #pragma unroll
            for (int cc = 0; cc < 2; ++cc) {
                um[r][cc] = fmaf(um[r][cc], DM, c[r][cc]);
                us[r][cc] = fmaf(us[r][cc], DS, c[r][cc]);
                float u = sav[r][cc] * (um[r][cc] - us[r][cc]);
                float s = (u > 1.f) ? 1.f : 0.f;
                sav[r][cc] *= (1.f - s);
                te[r][cc] += ((te[r][cc] != 0.f) || (um[r][cc] != 0.f)) ? 1.f : 0.f;
                lt[r][cc] += s * (te[r][cc] - 15.f);
                sv[r][cc] = s;
                if (pv) cnt += s;
            }
        float lmin = fminf(fminf(lt[0][0], lt[0][1]), fminf(lt[1][0], lt[1][1]));
        float o = fmaxf(fmaxf(lt[0][0] == lmin ? sv[0][0] : 0.f, lt[0][1] == lmin ? sv[0][1] : 0.f),
                        fmaxf(lt[1][0] == lmin ? sv[1][0] : 0.f, lt[1][1] == lmin ? sv[1][1] : 0.f));
        bool hit = (o != 0.f) && pv;
        unsigned long long bal = __ballot(hit);
        int k = tid & 63;
        if (k < 4) {
            int prow = (tid >> 6) * 4 + k;
            if (prow < 14) {
                unsigned wd = (unsigned)(bal >> (k * 16)) & 0x3FFFu;
                p1b[(((size_t)t * 128 + b) * 32 + oc) * 18 + prow + 2] = wd;
            }
        }
        if (hit) pm |= 1u << t;
    }

    unsigned pmw = pm;
    #pragma unroll
    for (int off = 32; off; off >>= 1) pmw |= __shfl_xor(pmw, off, 64);
    if ((tid & 63) == 0) wor[tid >> 6] = pmw;
    block_sum_atomic(cnt, red, &ssp[1]);
    if (tid == 0) flags[b * 32 + oc] = (unsigned short)(wor[0] | wor[1] | wor[2] | wor[3]);
}

// ---------------- conv2: bit-LUT, per-ic gated, zero barriers in t-loop ----------------
__launch_bounds__(256)
__global__ void k_conv2(const float* __restrict__ w2, const unsigned* __restrict__ p1b,
                        const unsigned short* __restrict__ flags,
                        unsigned short* __restrict__ p2m, float* __restrict__ ssp) {
    __shared__ float lut[5120];       // [ic*5+ky][32]
    __shared__ float red[4];
    int bo = blockIdx.x, b = bo >> 6, oc = bo & 63;
    int tid = threadIdx.x;
    int x = tid & 15, y = tid >> 4;
    bool valid = (x < 14) && (y < 14);
    int yy = valid ? y : 0;

    for (int e = tid; e < 5120; e += 256) {
        int m = e & 31, icky = e >> 5;
        const float* w = w2 + oc * 800 + icky * 5;
        float v = 0.f;
        #pragma unroll
        for (int kx = 0; kx < 5; ++kx)
            if ((m >> kx) & 1) v += w[kx];
        lut[e] = v;
    }
    unsigned fl = flags[b * 32 + (tid & 31)];
    __syncthreads();

    float um = 0.f, us = 0.f, sav = 1.f, te = 0.f, lt = 16.f, cnt = 0.f;
    unsigned pm = 0;
    bool pool_lane = valid && !(x & 1) && !(y & 1);

    for (int t = 0; t < 16; ++t) {
        unsigned actbm = (unsigned)__ballot(((fl >> t) & 1u) && ((tid & 63) < 32));
        float c = 0.f;
        unsigned bm = actbm;
        while (bm) {
            int ic = __builtin_ctz(bm); bm &= bm - 1;
            const unsigned* rp = p1b + (((size_t)t * 128 + b) * 32 + ic) * 18 + yy;
            unsigned r0 = rp[0] << 2, r1 = rp[1] << 2, r2 = rp[2] << 2,
                     r3 = rp[3] << 2, r4 = rp[4] << 2;
            unsigned win = ((r0 | r1 | r2 | r3 | r4) >> x) & 31u;
            if (valid && win) {
                int base = ic * 160;
                c += lut[base +       ((r0 >> x) & 31u)];
                c += lut[base + 32  + ((r1 >> x) & 31u)];
                c += lut[base + 64  + ((r2 >> x) & 31u)];
                c += lut[base + 96  + ((r3 >> x) & 31u)];
                c += lut[base + 128 + ((r4 >> x) & 31u)];
            }
        }
        um = fmaf(um, DM, c);
        us = fmaf(us, DS, c);
        float u = sav * (um - us);
        float s = (u > 1.f) ? 1.f : 0.f;
        sav *= (1.f - s);
        te += ((te != 0.f) || (um != 0.f)) ? 1.f : 0.f;
        lt += s * (te - 15.f);
        if (valid) cnt += s;
        float l2 = __shfl_xor(lt, 1, 64), s2 = __shfl_xor(s, 1, 64);
        float lm2 = fminf(lt, l2);
        float o2 = fmaxf(lt == lm2 ? s : 0.f, l2 == lm2 ? s2 : 0.f);
        float l4 = __shfl_xor(lm2, 16, 64), o4 = __shfl_xor(o2, 16, 64);
        float lm4 = fminf(lm2, l4);
        float o = fmaxf(lm2 == lm4 ? o2 : 0.f, l4 == lm4 ? o4 : 0.f);
        if (pool_lane && o != 0.f) pm |= 1u << t;
    }
    if (pool_lane)
        p2m[((size_t)b * 64 + oc) * 49 + (y >> 1) * 7 + (x >> 1)] = (unsigned short)pm;
    block_sum_atomic(cnt, red, &ssp[2]);
}

// ---------------- fc1 pre-activations: one block per (t,b), fully parallel ----------------
__launch_bounds__(640)
__global__ void k_fc1pre(const float* __restrict__ wt, const unsigned short* __restrict__ p2m,
                         float* __restrict__ C1) {
    __shared__ unsigned short s_m[3136];
    __shared__ int s_idx[3136];
    __shared__ int s_nnz;
    int bt = blockIdx.x;              // t*128 + b
    int b = bt & 127, t = bt >> 7;
    int tid = threadIdx.x;

    for (int k = tid; k < 3136; k += 640) s_m[k] = p2m[(size_t)b * 3136 + k];
    __syncthreads();
    if (tid < 64) {
        int count = 0;
        for (int o = 0; o < 64; ++o) {   // ascending (oc, pos): deterministic, same as R4
            unsigned v = (tid < 49) ? (unsigned)s_m[o * 49 + tid] : 0u;
            unsigned long long m = __ballot((v >> t) & 1u);
            if ((m >> tid) & 1ull)
                s_idx[count + __popcll(m & ((1ull << tid) - 1ull))] = o * 49 + tid;
            count += __popcll(m);
        }
        if (tid == 0) s_nnz = count;
    }
    __syncthreads();
    int nnz = s_nnz;

    if (tid < 600) {
        float a0 = 0.f, a1 = 0.f, a2 = 0.f, a3 = 0.f;
        int i = 0;
        for (; i + 4 <= nnz; i += 4) {
            a0 += wt[(size_t)s_idx[i]     * 600 + tid];
            a1 += wt[(size_t)s_idx[i + 1] * 600 + tid];
            a2 += wt[(size_t)s_idx[i + 2] * 600 + tid];
            a3 += wt[(size_t)s_idx[i + 3] * 600 + tid];
        }
        for (; i < nnz; ++i) a0 += wt[(size_t)s_idx[i] * 600 + tid];
        C1[(size_t)bt * 600 + tid] = (a0 + a1) + (a2 + a3);
    }
}

// ---------------- fc1 recurrence + fc2: registers only ----------------
__launch_bounds__(640)
__global__ void k_fc12b(const float* __restrict__ C1, const float* __restrict__ wf2,
                        float* __restrict__ out) {
    __shared__ unsigned short s_m1[600];
    __shared__ float red[16];
    __shared__ float s_c2[10];
    int b = blockIdx.x, tid = threadIdx.x;
    int w = tid >> 6, lane = tid & 63;

    float cnt1 = 0.f;
    if (tid < 600) {
        float c[16];
        #pragma unroll
        for (int t = 0; t < 16; ++t) c[t] = C1[((size_t)t * 128 + b) * 600 + tid];
        float um = 0.f, us = 0.f, sv = 1.f;
        unsigned msk = 0;
        #pragma unroll
        for (int t = 0; t < 16; ++t) {
            um = fmaf(um, DM, c[t]);
            us = fmaf(us, DS, c[t]);
            float u = sv * (um - us);
            float s = (u > 1.f) ? 1.f : 0.f;
            sv *= (1.f - s);
            msk |= (s != 0.f) ? (1u << t) : 0u;
            cnt1 += s;
        }
        s_m1[tid] = (unsigned short)msk;
    }
    block_sum_atomic(cnt1, red, &out[2563]);   // barriers inside: s_m1 now visible

    // fc2: wave w -> output neuron w; weights+masks preloaded to registers
    const float* wrow = wf2 + w * 600;
    float wv[10]; unsigned mv[10];
    #pragma unroll
    for (int i = 0; i < 10; ++i) {
        int j = lane + i * 64;
        bool ok = (j < 600);
        wv[i] = ok ? wrow[j] : 0.f;
        mv[i] = ok ? (unsigned)s_m1[j] : 0u;
    }
    float f2um = 0.f, f2us = 0.f, f2sv = 1.f;
    float tel = 0.f, ot = 16.f, ou = 0.f, cnt2 = 0.f;
    for (int t = 0; t < 16; ++t) {
        float a = 0.f;
        #pragma unroll
        for (int i = 0; i < 10; ++i) a += ((mv[i] >> t) & 1u) ? wv[i] : 0.f;
        #pragma unroll
        for (int o = 32; o; o >>= 1) a += __shfl_down(a, o, 64);
        if (lane == 0) {
            f2um = fmaf(f2um, DM, a);
            f2us = fmaf(f2us, DS, a);
            float u = f2sv * (f2um - f2us);
            float s2 = (u > 1.f) ? 1.f : 0.f;
            f2sv *= (1.f - s2);
            tel += ((tel != 0.f) || (u != 0.f)) ? 1.f : 0.f;
            ot += s2 * (tel - 16.f);
            ou += s2 * u;
            cnt2 += s2;
        }
    }
    if (lane == 0) {
        out[b * 10 + w] = ot;
        out[1280 + b * 10 + w] = ou;
        s_c2[w] = cnt2;
    }
    __syncthreads();
    if (tid == 0) {
        float tt = 0.f;
        for (int j = 0; j < 10; ++j) tt += s_c2[j];
        if (tt != 0.f) atomicAdd(&out[2564], tt);
    }
}

// ---------------- launch ----------------
extern "C" void kernel_launch(void* const* d_in, const int* in_sizes, int n_in,
                              void* d_out, int out_size, void* d_ws, size_t ws_size,
                              hipStream_t stream) {
    (void)in_sizes; (void)n_in; (void)out_size;
    if (ws_size < TOTALF * sizeof(float)) return;  // ~18 MB

    const float* inp = (const float*)d_in[0];
    const float* w1  = (const float*)d_in[1];
    const float* w2  = (const float*)d_in[2];
    const float* wf1 = (const float*)d_in[3];
    const float* wf2 = (const float*)d_in[4];
    float* ws  = (float*)d_ws;
    float* out = (float*)d_out;

    k_fill<<<3, 256, 0, stream>>>(out, 2565, 0.f);
    k_transpose<<<dim3(98, 19), 256, 0, stream>>>(wf1, ws + o_wt);

    k_encode<<<BATCH, 896, 0, stream>>>(inp, (unsigned*)(ws + o_inb), out + 2560);
    k_conv1<<<BATCH * 32, 256, 0, stream>>>(w1, (const unsigned*)(ws + o_inb),
                                            (unsigned*)(ws + o_p1b),
                                            (unsigned short*)(ws + o_flag), out + 2560);
    k_conv2<<<BATCH * 64, 256, 0, stream>>>(w2, (const unsigned*)(ws + o_p1b),
                                            (const unsigned short*)(ws + o_flag),
                                            (unsigned short*)(ws + o_p2m), out + 2560);
    k_fc1pre<<<16 * BATCH, 640, 0, stream>>>(ws + o_wt, (const unsigned short*)(ws + o_p2m),
                                             ws + o_c1);
    k_fc12b<<<BATCH, 640, 0, stream>>>(ws + o_c1, wf2, out);
}